// Round 6
// baseline (177.872 us; speedup 1.0000x reference)
//
#include <hip/hip_runtime.h>
#include <math.h>

#define Bv  4
#define Cv  64
#define DCv 32
#define Fv  128
#define Tv  512
#define FT  (Fv * Tv)

// Swizzled tile layout: column-owner dim tt (0..255), element dim k, float4 groups.
__device__ __forceinline__ int qoff4(int tt, int j) { return tt * 32 + ((j ^ (tt & 7)) << 2); }

// ---------------------------------------------------------------------------
// K1: conv1 + BN + PReLU -> Q (workspace, stored early) + per-half partial
// M = Q Q^T (raw sums) via swizzled LDS tile. grid (b,f,half)=1024 x 256.
// Conv phase designed for the compiler's 64-VGPR choice (x[16] batches).
// ---------------------------------------------------------------------------
__global__ __launch_bounds__(256, 4)
void k1_conv_m(const float* __restrict__ inp,
               const float* __restrict__ w1, const float* __restrict__ b1,
               const float* __restrict__ g1, const float* __restrict__ be1,
               const float* __restrict__ m1, const float* __restrict__ v1,
               const float* __restrict__ a1,
               float* __restrict__ Qws, float* __restrict__ Mws)
{
    __shared__ __align__(16) float sQ[256 * DCv];  // 32 KB
    __shared__ __align__(16) float sM[DCv * DCv];  // 4 KB raw sums
    __shared__ float sS1[DCv], sT1[DCv];

    const int tid  = threadIdx.x;
    const int bid  = blockIdx.x;
    const int half = bid & 1;
    const int bf   = bid >> 1;
    const int b    = bf >> 7;
    const int f    = bf & 127;

    if (tid < DCv) {
        float s = g1[tid] / sqrtf(v1[tid] + 1e-5f);
        sS1[tid] = s;
        sT1[tid] = (b1[tid] - m1[tid]) * s + be1[tid];
    }
    sM[tid] = 0.f; sM[tid + 256] = 0.f; sM[tid + 512] = 0.f; sM[tid + 768] = 0.f;
    const float alpha1 = a1[0];
    __syncthreads();

    const int t = half * 256 + tid;
    const float* px = inp + ((size_t)(b * Cv) * Fv + f) * Tv + t;

    float acc[DCv];
    #pragma unroll
    for (int c = 0; c < DCv; ++c) acc[c] = 0.f;

    // 4 input batches of 16 channels: x[16]+acc[32] fits the 64-reg budget
    #pragma unroll
    for (int kb = 0; kb < 4; ++kb) {
        float x[16];
        #pragma unroll
        for (int i = 0; i < 16; ++i) x[i] = px[(size_t)(kb * 16 + i) * FT];
        #pragma unroll 8
        for (int c = 0; c < DCv; ++c) {
            const float* wr = w1 + c * Cv + kb * 16;  // uniform -> scalar loads
            float a = acc[c];
            #pragma unroll
            for (int i = 0; i < 16; ++i) a = fmaf(wr[i], x[i], a);
            acc[c] = a;
        }
    }

    // BN + PReLU -> sQ (swizzled) + early global store (drains before barrier;
    // ~one-time latency, overlapped across 4 blocks/CU)
    float* qg = Qws + ((size_t)bf * Tv + t) * DCv;
    #pragma unroll
    for (int j = 0; j < 8; ++j) {
        float z0 = fmaf(acc[4*j+0], sS1[4*j+0], sT1[4*j+0]);
        float z1 = fmaf(acc[4*j+1], sS1[4*j+1], sT1[4*j+1]);
        float z2 = fmaf(acc[4*j+2], sS1[4*j+2], sT1[4*j+2]);
        float z3 = fmaf(acc[4*j+3], sS1[4*j+3], sT1[4*j+3]);
        float4 v;
        v.x = z0 >= 0.f ? z0 : alpha1 * z0;
        v.y = z1 >= 0.f ? z1 : alpha1 * z1;
        v.z = z2 >= 0.f ? z2 : alpha1 * z2;
        v.w = z3 >= 0.f ? z3 : alpha1 * z3;
        *(float4*)&sQ[qoff4(tid, j)] = v;
        *(float4*)&qg[j * 4] = v;
    }
    __syncthreads();

    // partial M over this half's 256 columns (raw sums)
    {
        const int w = tid >> 6, l = tid & 63;
        const int c1b = l >> 3;
        const int c2b = l & 7;
        float4 r0 = {0,0,0,0}, r1 = {0,0,0,0}, r2 = {0,0,0,0}, r3 = {0,0,0,0};
        const int kbase = w * 64;
        for (int i = 0; i < 64; ++i) {
            const int k = kbase + i;
            const float4 qa = *(const float4*)&sQ[qoff4(k, c1b)];
            const float4 qb = *(const float4*)&sQ[qoff4(k, c2b)];
            r0.x = fmaf(qa.x, qb.x, r0.x); r0.y = fmaf(qa.x, qb.y, r0.y);
            r0.z = fmaf(qa.x, qb.z, r0.z); r0.w = fmaf(qa.x, qb.w, r0.w);
            r1.x = fmaf(qa.y, qb.x, r1.x); r1.y = fmaf(qa.y, qb.y, r1.y);
            r1.z = fmaf(qa.y, qb.z, r1.z); r1.w = fmaf(qa.y, qb.w, r1.w);
            r2.x = fmaf(qa.z, qb.x, r2.x); r2.y = fmaf(qa.z, qb.y, r2.y);
            r2.z = fmaf(qa.z, qb.z, r2.z); r2.w = fmaf(qa.z, qb.w, r2.w);
            r3.x = fmaf(qa.w, qb.x, r3.x); r3.y = fmaf(qa.w, qb.y, r3.y);
            r3.z = fmaf(qa.w, qb.z, r3.z); r3.w = fmaf(qa.w, qb.w, r3.w);
        }
        float* m0 = &sM[(c1b * 4 + 0) * DCv + c2b * 4];
        float* m1r = &sM[(c1b * 4 + 1) * DCv + c2b * 4];
        float* m2r = &sM[(c1b * 4 + 2) * DCv + c2b * 4];
        float* m3r = &sM[(c1b * 4 + 3) * DCv + c2b * 4];
        atomicAdd(m0 + 0, r0.x); atomicAdd(m0 + 1, r0.y);
        atomicAdd(m0 + 2, r0.z); atomicAdd(m0 + 3, r0.w);
        atomicAdd(m1r + 0, r1.x); atomicAdd(m1r + 1, r1.y);
        atomicAdd(m1r + 2, r1.z); atomicAdd(m1r + 3, r1.w);
        atomicAdd(m2r + 0, r2.x); atomicAdd(m2r + 1, r2.y);
        atomicAdd(m2r + 2, r2.z); atomicAdd(m2r + 3, r2.w);
        atomicAdd(m3r + 0, r3.x); atomicAdd(m3r + 1, r3.y);
        atomicAdd(m3r + 2, r3.z); atomicAdd(m3r + 3, r3.w);
    }
    __syncthreads();

    float4 mv = *(const float4*)&sM[tid * 4];
    *(float4*)&Mws[(size_t)bid * 1024 + tid * 4] = mv;
}

// ---------------------------------------------------------------------------
// K1c: Mfull[bf][32][32] = (Mpart0 + Mpart1) / sqrt(32).  512 x 256, float4.
// ---------------------------------------------------------------------------
__global__ __launch_bounds__(256, 4)
void k1c_combine(const float* __restrict__ Mws, float* __restrict__ Mfull)
{
    const float INV = 0.17677669529663687f;  // 1/sqrt(32)
    const int gid = blockIdx.x * 256 + threadIdx.x;   // one float4 each
    const int bf  = gid >> 8;
    const int j   = gid & 255;
    const float4 a = *(const float4*)&Mws[(size_t)bf * 2048 + j * 4];
    const float4 c = *(const float4*)&Mws[(size_t)bf * 2048 + 1024 + j * 4];
    float4 o;
    o.x = (a.x + c.x) * INV; o.y = (a.y + c.y) * INV;
    o.z = (a.z + c.z) * INV; o.w = (a.w + c.w) * INV;
    *(float4*)&Mfull[(size_t)bf * 1024 + j * 4] = o;
}

// ---------------------------------------------------------------------------
// K2a: per-(bf, 128-t-chunk) softmax stats. O = Mfull*q with M via SCALAR
// loads (block-uniform). 16 KB transpose tile, 2 waves reduce 16 rows each.
// grid 2048 x 128 -> 8 blocks/CU, 16 waves/CU.
// ---------------------------------------------------------------------------
__global__ __launch_bounds__(128, 2)
void k2a_stats(const float* __restrict__ Qws, const float* __restrict__ Mfull,
               float* __restrict__ Smx, float* __restrict__ Ssum)
{
    __shared__ __align__(16) float sO[DCv][128];   // 16 KB

    const int tid   = threadIdx.x;
    const int bid   = blockIdx.x;
    const int bf    = bid >> 2;
    const int chunk = bid & 3;
    const int f     = bf & 127;
    const int t     = chunk * 128 + tid;

    float q[DCv];
    const float* qg = Qws + ((size_t)bf * Tv + t) * DCv;
    #pragma unroll
    for (int j = 0; j < 8; ++j) {
        float4 v = *(const float4*)&qg[j * 4];
        q[4*j] = v.x; q[4*j+1] = v.y; q[4*j+2] = v.z; q[4*j+3] = v.w;
    }

    int limit = f + (Tv - Fv + 1);
    if (limit > Tv) limit = Tv;
    const bool valid = t < limit;

    const float* Mg = Mfull + (size_t)bf * 1024;   // block-uniform -> scalar loads
    #pragma unroll 4
    for (int c = 0; c < DCv; ++c) {
        const float* mr = Mg + c * DCv;
        float a = 0.f;
        #pragma unroll
        for (int k = 0; k < DCv; ++k) a = fmaf(mr[k], q[k], a);
        sO[c][tid] = valid ? a : -INFINITY;
    }
    __syncthreads();

    const int w = tid >> 6, l = tid & 63;
    #pragma unroll
    for (int r = 0; r < 16; ++r) {
        const int c = w * 16 + r;
        float v0 = sO[c][l], v1 = sO[c][64 + l];
        float mx = fmaxf(v0, v1);
        #pragma unroll
        for (int s = 1; s < 64; s <<= 1) mx = fmaxf(mx, __shfl_xor(mx, s));
        float sum = __expf(v0 - mx) + __expf(v1 - mx);
        #pragma unroll
        for (int s = 1; s < 64; s <<= 1) sum += __shfl_xor(sum, s);
        if (l == 0) {
            Smx [(size_t)bf * 128 + c * 4 + chunk] = mx;
            Ssum[(size_t)bf * 128 + c * 4 + chunk] = sum;
        }
    }
}

// ---------------------------------------------------------------------------
// K2b: streaming output. Combine chunk stats (tiny), then per-thread:
// q -> O (scalar-M) -> P -> conv2 + BN + PReLU + residual -> out.
// ONE barrier; no big LDS. grid 1024 x 256.
// ---------------------------------------------------------------------------
__global__ __launch_bounds__(256, 2)
void k2b_out(const float* __restrict__ inp,
             const float* __restrict__ Qws, const float* __restrict__ Mfull,
             const float* __restrict__ Smx, const float* __restrict__ Ssum,
             const float* __restrict__ wp, const float* __restrict__ bp,
             const float* __restrict__ g2, const float* __restrict__ be2,
             const float* __restrict__ m2, const float* __restrict__ v2,
             const float* __restrict__ a2,
             float* __restrict__ out)
{
    __shared__ float sMx[DCv], sRZ[DCv];
    __shared__ float sS2[Cv], sT2[Cv];

    const int tid = threadIdx.x;
    const int bid = blockIdx.x;
    const int bf  = bid >> 1;
    const int b   = bf >> 7;
    const int f   = bf & 127;
    const int t   = (bid & 1) * 256 + tid;

    if (tid < DCv) {
        const float* pm = Smx  + (size_t)bf * 128 + tid * 4;
        const float* ps = Ssum + (size_t)bf * 128 + tid * 4;
        float m0 = pm[0], m1 = pm[1], m2_ = pm[2], m3 = pm[3];
        float mx = fmaxf(fmaxf(m0, m1), fmaxf(m2_, m3));
        float Z = ps[0] * __expf(m0 - mx) + ps[1] * __expf(m1 - mx)
                + ps[2] * __expf(m2_ - mx) + ps[3] * __expf(m3 - mx);
        sMx[tid] = mx;
        sRZ[tid] = 1.f / Z;
    } else if (tid >= 32 && tid < 32 + Cv) {
        const int o = tid - 32;
        float s = g2[o] / sqrtf(v2[o] + 1e-5f);
        sS2[o] = s;
        sT2[o] = (bp[o] - m2[o]) * s + be2[o];
    }
    const float alpha2 = a2[0];
    __syncthreads();

    float q[DCv];
    const float* qg = Qws + ((size_t)bf * Tv + t) * DCv;
    #pragma unroll
    for (int j = 0; j < 8; ++j) {
        float4 v = *(const float4*)&qg[j * 4];
        q[4*j] = v.x; q[4*j+1] = v.y; q[4*j+2] = v.z; q[4*j+3] = v.w;
    }

    int limit = f + (Tv - Fv + 1);
    if (limit > Tv) limit = Tv;
    const bool valid = t < limit;

    // P[c] = softmax value; M via scalar loads (block-uniform)
    const float* Mg = Mfull + (size_t)bf * 1024;
    float P[DCv];
    #pragma unroll 4
    for (int c = 0; c < DCv; ++c) {
        const float* mr = Mg + c * DCv;
        float a = 0.f;
        #pragma unroll
        for (int k = 0; k < DCv; ++k) a = fmaf(mr[k], q[k], a);
        P[c] = valid ? __expf(a - sMx[c]) * sRZ[c] : 0.f;
    }

    // prefetch residual half 0 — hidden under conv2 half-0's FMA block
    float rin0[32];
    const float* pin = inp + ((size_t)(b * Cv) * Fv + f) * Tv + t;
    #pragma unroll
    for (int i = 0; i < 32; ++i) rin0[i] = pin[(size_t)i * FT];

    float* pot = out + ((size_t)(b * Cv) * Fv + f) * Tv + t;
    #pragma unroll 4
    for (int oo = 0; oo < 32; ++oo) {
        const float* wr = wp + oo * DCv;  // uniform -> scalar loads
        float a = 0.f;
        #pragma unroll
        for (int c2 = 0; c2 < DCv; ++c2) a = fmaf(wr[c2], P[c2], a);
        float z = fmaf(a, sS2[oo], sT2[oo]);
        z = z >= 0.f ? z : alpha2 * z;
        pot[(size_t)oo * FT] = z + rin0[oo];
    }

    float rin1[32];
    #pragma unroll
    for (int i = 0; i < 32; ++i) rin1[i] = pin[(size_t)(i + 32) * FT];

    #pragma unroll 4
    for (int oo = 0; oo < 32; ++oo) {
        const int o = 32 + oo;
        const float* wr = wp + o * DCv;
        float a = 0.f;
        #pragma unroll
        for (int c2 = 0; c2 < DCv; ++c2) a = fmaf(wr[c2], P[c2], a);
        float z = fmaf(a, sS2[o], sT2[o]);
        z = z >= 0.f ? z : alpha2 * z;
        pot[(size_t)o * FT] = z + rin1[oo];
    }
}

extern "C" void kernel_launch(void* const* d_in, const int* in_sizes, int n_in,
                              void* d_out, int out_size, void* d_ws, size_t ws_size,
                              hipStream_t stream) {
    const float* inp = (const float*)d_in[0];
    const float* w1  = (const float*)d_in[1];
    const float* b1  = (const float*)d_in[2];
    const float* g1  = (const float*)d_in[3];
    const float* be1 = (const float*)d_in[4];
    const float* m1  = (const float*)d_in[5];
    const float* v1  = (const float*)d_in[6];
    const float* a1  = (const float*)d_in[7];
    const float* wp  = (const float*)d_in[8];
    const float* bp  = (const float*)d_in[9];
    const float* g2  = (const float*)d_in[10];
    const float* be2 = (const float*)d_in[11];
    const float* m2  = (const float*)d_in[12];
    const float* v2  = (const float*)d_in[13];
    const float* a2  = (const float*)d_in[14];

    float* Qws   = (float*)d_ws;                            // 8,388,608 f = 33.6 MB
    float* Mws   = Qws   + (size_t)Bv * Fv * Tv * DCv;      // 1,048,576 f = 4.2 MB
    float* Mfull = Mws   + (size_t)1024 * 1024;             //   524,288 f = 2.1 MB
    float* Smx   = Mfull + (size_t)512 * 1024;              //    65,536 f
    float* Ssum  = Smx   + (size_t)512 * 128;               //    65,536 f

    k1_conv_m<<<dim3(Bv * Fv * 2), dim3(256), 0, stream>>>(
        inp, w1, b1, g1, be1, m1, v1, a1, Qws, Mws);
    k1c_combine<<<dim3(512), dim3(256), 0, stream>>>(Mws, Mfull);
    k2a_stats<<<dim3(Bv * Fv * 4), dim3(128), 0, stream>>>(Qws, Mfull, Smx, Ssum);
    k2b_out<<<dim3(Bv * Fv * 2), dim3(256), 0, stream>>>(
        inp, Qws, Mfull, Smx, Ssum, wp, bp, g2, be2, m2, v2, a2, (float*)d_out);
}

// Round 7
// 126.247 us; speedup vs baseline: 1.4089x; 1.4089x over previous
//
#include <hip/hip_runtime.h>
#include <math.h>

#define Bv  4
#define Cv  64
#define DCv 32
#define Fv  128
#define Tv  512
#define FT  (Fv * Tv)

// ---------------------------------------------------------------------------
// K1: PURE conv1 + BN + PReLU -> Q. grid (b,f,half)=1024 x 256. Software-
// pipelined 8-channel batches (xa/xb double buffer, statically named so the
// arrays stay in registers). Live set ~56 regs -> fits compiler's 64-VGPR pick.
// ---------------------------------------------------------------------------
#define LOADX(arr, kb) { _Pragma("unroll") \
    for (int i = 0; i < 8; ++i) arr[i] = px[(size_t)((kb) * 8 + i) * FT]; }
#define CONVB(arr, kb) { _Pragma("unroll") \
    for (int c = 0; c < DCv; ++c) { \
        const float* wr = w1 + c * Cv + (kb) * 8; \
        float a = acc[c]; \
        _Pragma("unroll") for (int i = 0; i < 8; ++i) a = fmaf(wr[i], arr[i], a); \
        acc[c] = a; } }

__global__ __launch_bounds__(256, 4)
void k1_conv(const float* __restrict__ inp,
             const float* __restrict__ w1, const float* __restrict__ b1,
             const float* __restrict__ g1, const float* __restrict__ be1,
             const float* __restrict__ m1, const float* __restrict__ v1,
             const float* __restrict__ a1,
             float* __restrict__ Qws)
{
    __shared__ float sS1[DCv], sT1[DCv];

    const int tid  = threadIdx.x;
    const int bid  = blockIdx.x;
    const int half = bid & 1;
    const int bf   = bid >> 1;
    const int b    = bf >> 7;
    const int f    = bf & 127;

    if (tid < DCv) {
        float s = g1[tid] / sqrtf(v1[tid] + 1e-5f);
        sS1[tid] = s;
        sT1[tid] = (b1[tid] - m1[tid]) * s + be1[tid];
    }
    const float alpha1 = a1[0];
    __syncthreads();

    const int t = half * 256 + tid;
    const float* px = inp + ((size_t)(b * Cv) * Fv + f) * Tv + t;

    float acc[DCv];
    #pragma unroll
    for (int c = 0; c < DCv; ++c) acc[c] = 0.f;

    float xa[8], xb[8];
    LOADX(xa, 0);
    LOADX(xb, 1); CONVB(xa, 0);
    LOADX(xa, 2); CONVB(xb, 1);
    LOADX(xb, 3); CONVB(xa, 2);
    LOADX(xa, 4); CONVB(xb, 3);
    LOADX(xb, 5); CONVB(xa, 4);
    LOADX(xa, 6); CONVB(xb, 5);
    LOADX(xb, 7); CONVB(xa, 6);
    CONVB(xb, 7);

    float* qg = Qws + ((size_t)bf * Tv + t) * DCv;
    #pragma unroll
    for (int j = 0; j < 8; ++j) {
        float z0 = fmaf(acc[4*j+0], sS1[4*j+0], sT1[4*j+0]);
        float z1 = fmaf(acc[4*j+1], sS1[4*j+1], sT1[4*j+1]);
        float z2 = fmaf(acc[4*j+2], sS1[4*j+2], sT1[4*j+2]);
        float z3 = fmaf(acc[4*j+3], sS1[4*j+3], sT1[4*j+3]);
        float4 v;
        v.x = z0 >= 0.f ? z0 : alpha1 * z0;
        v.y = z1 >= 0.f ? z1 : alpha1 * z1;
        v.z = z2 >= 0.f ? z2 : alpha1 * z2;
        v.w = z3 >= 0.f ? z3 : alpha1 * z3;
        *(float4*)&qg[j * 4] = v;
    }
}

// ---------------------------------------------------------------------------
// KM: partial M. grid (bf, 4 k-slices) = 2048 blocks x 64 (one wave). Lane l
// computes the 4x4 tile (c1b,c2b) over its slice's 128 k's, reading Q from
// global (L2-hot). No atomics, no barriers, no LDS -> pure latency-hidden.
// ---------------------------------------------------------------------------
__global__ __launch_bounds__(64)
void km_partial(const float* __restrict__ Qws, float* __restrict__ Mpart)
{
    const int bid   = blockIdx.x;
    const int slice = bid & 3;
    const int bf    = bid >> 2;
    const int l     = threadIdx.x;
    const int c1b   = l >> 3;
    const int c2b   = l & 7;

    const float* qb_ = Qws + ((size_t)bf * Tv + slice * 128) * DCv;
    float4 r0 = {0,0,0,0}, r1 = {0,0,0,0}, r2 = {0,0,0,0}, r3 = {0,0,0,0};
    #pragma unroll 4
    for (int i = 0; i < 128; ++i) {
        const float4 qa = *(const float4*)&qb_[i * 32 + c1b * 4];
        const float4 qb = *(const float4*)&qb_[i * 32 + c2b * 4];
        r0.x = fmaf(qa.x, qb.x, r0.x); r0.y = fmaf(qa.x, qb.y, r0.y);
        r0.z = fmaf(qa.x, qb.z, r0.z); r0.w = fmaf(qa.x, qb.w, r0.w);
        r1.x = fmaf(qa.y, qb.x, r1.x); r1.y = fmaf(qa.y, qb.y, r1.y);
        r1.z = fmaf(qa.y, qb.z, r1.z); r1.w = fmaf(qa.y, qb.w, r1.w);
        r2.x = fmaf(qa.z, qb.x, r2.x); r2.y = fmaf(qa.z, qb.y, r2.y);
        r2.z = fmaf(qa.z, qb.z, r2.z); r2.w = fmaf(qa.z, qb.w, r2.w);
        r3.x = fmaf(qa.w, qb.x, r3.x); r3.y = fmaf(qa.w, qb.y, r3.y);
        r3.z = fmaf(qa.w, qb.z, r3.z); r3.w = fmaf(qa.w, qb.w, r3.w);
    }
    float* mp = Mpart + (size_t)bid * 1024;
    *(float4*)&mp[(c1b * 4 + 0) * DCv + c2b * 4] = r0;
    *(float4*)&mp[(c1b * 4 + 1) * DCv + c2b * 4] = r1;
    *(float4*)&mp[(c1b * 4 + 2) * DCv + c2b * 4] = r2;
    *(float4*)&mp[(c1b * 4 + 3) * DCv + c2b * 4] = r3;
}

// ---------------------------------------------------------------------------
// KMc: Mfull = (sum of 4 partials) / sqrt(32). 2048 x 256, one float each.
// ---------------------------------------------------------------------------
__global__ __launch_bounds__(256)
void kmc_combine(const float* __restrict__ Mpart, float* __restrict__ Mfull)
{
    const float INV = 0.17677669529663687f;  // 1/sqrt(32)
    const int gid = blockIdx.x * 256 + threadIdx.x;
    const int bf  = gid >> 10;
    const int j   = gid & 1023;
    const float* mp = Mpart + (size_t)bf * 4096 + j;
    float s = (mp[0] + mp[1024]) + (mp[2048] + mp[3072]);
    Mfull[gid] = s * INV;
}

// ---------------------------------------------------------------------------
// K2: fused stats + output. grid (b,f)=512 x 512 threads. O = Mfull*q with M
// via SCALAR loads (block-uniform, zero LDS/VMEM-per-lane); softmax stats via
// 16 KB chunked transpose tile (4 chunks x 8 rows, wave-per-row); conv2 + BN +
// PReLU + residual with rin prefetch between halves. (512,2) -> no 64-reg trap.
// ---------------------------------------------------------------------------
__global__ __launch_bounds__(512, 2)
void k2_out(const float* __restrict__ inp,
            const float* __restrict__ Qws, const float* __restrict__ Mfull,
            const float* __restrict__ wp, const float* __restrict__ bp,
            const float* __restrict__ g2, const float* __restrict__ be2,
            const float* __restrict__ m2, const float* __restrict__ v2,
            const float* __restrict__ a2,
            float* __restrict__ out)
{
    __shared__ __align__(16) float sT[8][Tv];   // 16 KB transpose chunk
    __shared__ float sMx[DCv], sRZ[DCv];
    __shared__ float sS2[Cv], sT2[Cv];

    const int tid = threadIdx.x;
    const int bf  = blockIdx.x;
    const int b   = bf >> 7;
    const int f   = bf & 127;
    const int t   = tid;
    const int l   = tid & 63, w = tid >> 6;

    // q column (contiguous 128 B/thread) — issue first
    float q[DCv];
    const float* qg = Qws + ((size_t)bf * Tv + t) * DCv;
    #pragma unroll
    for (int j = 0; j < 8; ++j) {
        float4 v = *(const float4*)&qg[j * 4];
        q[4*j] = v.x; q[4*j+1] = v.y; q[4*j+2] = v.z; q[4*j+3] = v.w;
    }

    if (tid < Cv) {
        float s = g2[tid] / sqrtf(v2[tid] + 1e-5f);
        sS2[tid] = s;
        sT2[tid] = (bp[tid] - m2[tid]) * s + be2[tid];
    }
    const float alpha2 = a2[0];

    // O = Mfull * q ; M rows via scalar loads, 4 independent FMA chains per row
    const float* Mg = Mfull + (size_t)bf * 1024;
    float O[DCv];
    #pragma unroll 4
    for (int c = 0; c < DCv; ++c) {
        const float* mr = Mg + c * DCv;
        float a0 = 0.f, a1 = 0.f, a2_ = 0.f, a3 = 0.f;
        #pragma unroll
        for (int k = 0; k < 8; ++k) {
            a0  = fmaf(mr[k],      q[k],      a0);
            a1  = fmaf(mr[k + 8],  q[k + 8],  a1);
            a2_ = fmaf(mr[k + 16], q[k + 16], a2_);
            a3  = fmaf(mr[k + 24], q[k + 24], a3);
        }
        O[c] = (a0 + a1) + (a2_ + a3);
    }

    // causal mask: valid iff t < f + 385
    int limit = f + (Tv - Fv + 1);
    if (limit > Tv) limit = Tv;
    if (t >= limit) {
        #pragma unroll
        for (int c = 0; c < DCv; ++c) O[c] = -INFINITY;
    }

    // chunked transpose softmax stats: 4 chunks x 8 channels
    #pragma unroll
    for (int ch = 0; ch < 4; ++ch) {
        #pragma unroll
        for (int r = 0; r < 8; ++r) sT[r][t] = O[ch * 8 + r];
        __syncthreads();
        {
            const int c = ch * 8 + w;           // wave w owns one row
            float v[8];
            #pragma unroll
            for (int k = 0; k < 8; ++k) v[k] = sT[w][(k << 6) + l];
            float mx = fmaxf(fmaxf(fmaxf(v[0], v[1]), fmaxf(v[2], v[3])),
                             fmaxf(fmaxf(v[4], v[5]), fmaxf(v[6], v[7])));
            #pragma unroll
            for (int s = 1; s < 64; s <<= 1) mx = fmaxf(mx, __shfl_xor(mx, s));
            float sum = 0.f;
            #pragma unroll
            for (int k = 0; k < 8; ++k) sum += __expf(v[k] - mx);
            #pragma unroll
            for (int s = 1; s < 64; s <<= 1) sum += __shfl_xor(sum, s);
            if (l == 0) { sMx[c] = mx; sRZ[c] = 1.f / sum; }
        }
        __syncthreads();
    }

    // P in registers (masked O=-inf -> 0)
    #pragma unroll
    for (int c = 0; c < DCv; ++c) O[c] = __expf(O[c] - sMx[c]) * sRZ[c];

    // conv2 + BN + PReLU + residual; rin prefetched per half
    const float* pin = inp + ((size_t)(b * Cv) * Fv + f) * Tv + t;
    float* pot       = out + ((size_t)(b * Cv) * Fv + f) * Tv + t;

    float rin0[32];
    #pragma unroll
    for (int i = 0; i < 32; ++i) rin0[i] = pin[(size_t)i * FT];

    #pragma unroll 4
    for (int oo = 0; oo < 32; ++oo) {
        const float* wr = wp + oo * DCv;  // uniform -> scalar loads
        float a0 = 0.f, a1 = 0.f, a2_ = 0.f, a3 = 0.f;
        #pragma unroll
        for (int k = 0; k < 8; ++k) {
            a0  = fmaf(wr[k],      O[k],      a0);
            a1  = fmaf(wr[k + 8],  O[k + 8],  a1);
            a2_ = fmaf(wr[k + 16], O[k + 16], a2_);
            a3  = fmaf(wr[k + 24], O[k + 24], a3);
        }
        float z = fmaf((a0 + a1) + (a2_ + a3), sS2[oo], sT2[oo]);
        z = z >= 0.f ? z : alpha2 * z;
        pot[(size_t)oo * FT] = z + rin0[oo];
    }

    float rin1[32];
    #pragma unroll
    for (int i = 0; i < 32; ++i) rin1[i] = pin[(size_t)(i + 32) * FT];

    #pragma unroll 4
    for (int oo = 0; oo < 32; ++oo) {
        const int o = 32 + oo;
        const float* wr = wp + o * DCv;
        float a0 = 0.f, a1 = 0.f, a2_ = 0.f, a3 = 0.f;
        #pragma unroll
        for (int k = 0; k < 8; ++k) {
            a0  = fmaf(wr[k],      O[k],      a0);
            a1  = fmaf(wr[k + 8],  O[k + 8],  a1);
            a2_ = fmaf(wr[k + 16], O[k + 16], a2_);
            a3  = fmaf(wr[k + 24], O[k + 24], a3);
        }
        float z = fmaf((a0 + a1) + (a2_ + a3), sS2[o], sT2[o]);
        z = z >= 0.f ? z : alpha2 * z;
        pot[(size_t)o * FT] = z + rin1[oo];
    }
}

extern "C" void kernel_launch(void* const* d_in, const int* in_sizes, int n_in,
                              void* d_out, int out_size, void* d_ws, size_t ws_size,
                              hipStream_t stream) {
    const float* inp = (const float*)d_in[0];
    const float* w1  = (const float*)d_in[1];
    const float* b1  = (const float*)d_in[2];
    const float* g1  = (const float*)d_in[3];
    const float* be1 = (const float*)d_in[4];
    const float* m1  = (const float*)d_in[5];
    const float* v1  = (const float*)d_in[6];
    const float* a1  = (const float*)d_in[7];
    const float* wp  = (const float*)d_in[8];
    const float* bp  = (const float*)d_in[9];
    const float* g2  = (const float*)d_in[10];
    const float* be2 = (const float*)d_in[11];
    const float* m2  = (const float*)d_in[12];
    const float* v2  = (const float*)d_in[13];
    const float* a2  = (const float*)d_in[14];

    float* Qws   = (float*)d_ws;                            // 8,388,608 f = 33.6 MB
    float* Mpart = Qws   + (size_t)Bv * Fv * Tv * DCv;      // 2,097,152 f =  8.4 MB
    float* Mfull = Mpart + (size_t)2048 * 1024;             //   524,288 f =  2.1 MB

    k1_conv<<<dim3(Bv * Fv * 2), dim3(256), 0, stream>>>(
        inp, w1, b1, g1, be1, m1, v1, a1, Qws);
    km_partial<<<dim3(Bv * Fv * 4), dim3(64), 0, stream>>>(Qws, Mpart);
    kmc_combine<<<dim3(2048), dim3(256), 0, stream>>>(Mpart, Mfull);
    k2_out<<<dim3(Bv * Fv), dim3(512), 0, stream>>>(
        inp, Qws, Mfull, wp, bp, g2, be2, m2, v2, a2, (float*)d_out);
}

// Round 8
// 126.180 us; speedup vs baseline: 1.4097x; 1.0005x over previous
//
#include <hip/hip_runtime.h>
#include <math.h>

#define Bv  4
#define Cv  64
#define DCv 32
#define Fv  128
#define Tv  512
#define FT  (Fv * 512)

// ---------------------------------------------------------------------------
// K1: PURE conv1 + BN + PReLU -> Q. grid (b,f,half)=1024 x 256.
// 4-deep software pipeline (xa..xd, statically named). Live set ~76 regs, so
// we FORCE the 128-VGPR budget via a 34 KB LDS pad (=> 4 blocks/CU => 4
// waves/SIMD => budget 512/4 = 128). Without the pad the allocator targets 8
// waves/SIMD and 64 regs, which spills this live set (round-4 lesson).
// ---------------------------------------------------------------------------
#define LOADX(arr, kb) { _Pragma("unroll") \
    for (int i = 0; i < 8; ++i) arr[i] = px[(size_t)((kb) * 8 + i) * FT]; }
#define CONVB(arr, kb) { _Pragma("unroll") \
    for (int c = 0; c < DCv; ++c) { \
        const float* wr = w1 + c * Cv + (kb) * 8; \
        float a = acc[c]; \
        _Pragma("unroll") for (int i = 0; i < 8; ++i) a = fmaf(wr[i], arr[i], a); \
        acc[c] = a; } }

__global__ __launch_bounds__(256, 2)
void k1_conv(const float* __restrict__ inp,
             const float* __restrict__ w1, const float* __restrict__ b1,
             const float* __restrict__ g1, const float* __restrict__ be1,
             const float* __restrict__ m1, const float* __restrict__ v1,
             const float* __restrict__ a1,
             float* __restrict__ Qws)
{
    __shared__ float sS1[DCv], sT1[DCv];
    __shared__ float sPad[8448];   // 33 KB occupancy governor (see header comment)

    const int tid  = threadIdx.x;
    const int bid  = blockIdx.x;
    const int half = bid & 1;
    const int bf   = bid >> 1;
    const int b    = bf >> 7;
    const int f    = bf & 127;

    if (tid < DCv) {
        float s = g1[tid] / sqrtf(v1[tid] + 1e-5f);
        sS1[tid] = s;
        sT1[tid] = (b1[tid] - m1[tid]) * s + be1[tid];
    }
    const float alpha1 = a1[0];
    if (tid == 0) sPad[bid & 8191] = alpha1;  // keep sPad alive (runtime index)
    __syncthreads();

    const int t = half * 256 + tid;
    const float* px = inp + ((size_t)(b * Cv) * Fv + f) * Tv + t;

    float acc[DCv];
    #pragma unroll
    for (int c = 0; c < DCv; ++c) acc[c] = 0.f;

    float xa[8], xb[8], xc[8], xd[8];
    LOADX(xa, 0); LOADX(xb, 1); LOADX(xc, 2); LOADX(xd, 3);
    CONVB(xa, 0); LOADX(xa, 4);
    CONVB(xb, 1); LOADX(xb, 5);
    CONVB(xc, 2); LOADX(xc, 6);
    CONVB(xd, 3); LOADX(xd, 7);
    CONVB(xa, 4);
    CONVB(xb, 5);
    CONVB(xc, 6);
    CONVB(xd, 7);

    float* qg = Qws + ((size_t)bf * Tv + t) * DCv;
    #pragma unroll
    for (int j = 0; j < 8; ++j) {
        float z0 = fmaf(acc[4*j+0], sS1[4*j+0], sT1[4*j+0]);
        float z1 = fmaf(acc[4*j+1], sS1[4*j+1], sT1[4*j+1]);
        float z2 = fmaf(acc[4*j+2], sS1[4*j+2], sT1[4*j+2]);
        float z3 = fmaf(acc[4*j+3], sS1[4*j+3], sT1[4*j+3]);
        float4 v;
        v.x = z0 >= 0.f ? z0 : alpha1 * z0;
        v.y = z1 >= 0.f ? z1 : alpha1 * z1;
        v.z = z2 >= 0.f ? z2 : alpha1 * z2;
        v.w = z3 >= 0.f ? z3 : alpha1 * z3;
        *(float4*)&qg[j * 4] = v;
    }
}

// ---------------------------------------------------------------------------
// KM: M = Q Q^T / sqrt(32), one block per bf. 256 threads = 4 k-slice groups
// x 64 lanes; lane computes a 4x4 tile over its slice's 128 k's (Q from
// global, L2-hot), partials combined through 16 KB LDS. No atomics, 1 barrier.
// ---------------------------------------------------------------------------
__global__ __launch_bounds__(256)
void km_build(const float* __restrict__ Qws, float* __restrict__ Mfull)
{
    __shared__ __align__(16) float sP[4][1024];  // 16 KB

    const int tid   = threadIdx.x;
    const int bf    = blockIdx.x;
    const int slice = tid >> 6;
    const int l     = tid & 63;
    const int c1b   = l >> 3;
    const int c2b   = l & 7;

    const float* qp = Qws + ((size_t)bf * Tv + slice * 128) * DCv;
    float4 r0 = {0,0,0,0}, r1 = {0,0,0,0}, r2 = {0,0,0,0}, r3 = {0,0,0,0};
    #pragma unroll 4
    for (int i = 0; i < 128; ++i) {
        const float4 qa = *(const float4*)&qp[i * 32 + c1b * 4];
        const float4 qb = *(const float4*)&qp[i * 32 + c2b * 4];
        r0.x = fmaf(qa.x, qb.x, r0.x); r0.y = fmaf(qa.x, qb.y, r0.y);
        r0.z = fmaf(qa.x, qb.z, r0.z); r0.w = fmaf(qa.x, qb.w, r0.w);
        r1.x = fmaf(qa.y, qb.x, r1.x); r1.y = fmaf(qa.y, qb.y, r1.y);
        r1.z = fmaf(qa.y, qb.z, r1.z); r1.w = fmaf(qa.y, qb.w, r1.w);
        r2.x = fmaf(qa.z, qb.x, r2.x); r2.y = fmaf(qa.z, qb.y, r2.y);
        r2.z = fmaf(qa.z, qb.z, r2.z); r2.w = fmaf(qa.z, qb.w, r2.w);
        r3.x = fmaf(qa.w, qb.x, r3.x); r3.y = fmaf(qa.w, qb.y, r3.y);
        r3.z = fmaf(qa.w, qb.z, r3.z); r3.w = fmaf(qa.w, qb.w, r3.w);
    }
    *(float4*)&sP[slice][(c1b * 4 + 0) * DCv + c2b * 4] = r0;
    *(float4*)&sP[slice][(c1b * 4 + 1) * DCv + c2b * 4] = r1;
    *(float4*)&sP[slice][(c1b * 4 + 2) * DCv + c2b * 4] = r2;
    *(float4*)&sP[slice][(c1b * 4 + 3) * DCv + c2b * 4] = r3;
    __syncthreads();

    const float INV = 0.17677669529663687f;  // 1/sqrt(32)
    float4 v0 = *(const float4*)&sP[0][tid * 4];
    float4 v1 = *(const float4*)&sP[1][tid * 4];
    float4 v2 = *(const float4*)&sP[2][tid * 4];
    float4 v3 = *(const float4*)&sP[3][tid * 4];
    float4 o;
    o.x = ((v0.x + v1.x) + (v2.x + v3.x)) * INV;
    o.y = ((v0.y + v1.y) + (v2.y + v3.y)) * INV;
    o.z = ((v0.z + v1.z) + (v2.z + v3.z)) * INV;
    o.w = ((v0.w + v1.w) + (v2.w + v3.w)) * INV;
    *(float4*)&Mfull[(size_t)bf * 1024 + tid * 4] = o;
}

// ---------------------------------------------------------------------------
// K2: fused stats + output. grid (b,f)=512 x 512 threads. O = Mfull*q via
// SCALAR M loads; softmax via ONE 32-row transpose tile (67 KB LDS => 2
// blocks/CU => 128-VGPR budget, the round-7 fix) with only 2 barriers;
// conv2 + BN + PReLU + residual with rin prefetch per half.
// ---------------------------------------------------------------------------
__global__ __launch_bounds__(512, 2)
void k2_out(const float* __restrict__ inp,
            const float* __restrict__ Qws, const float* __restrict__ Mfull,
            const float* __restrict__ wp, const float* __restrict__ bp,
            const float* __restrict__ g2, const float* __restrict__ be2,
            const float* __restrict__ m2, const float* __restrict__ v2,
            const float* __restrict__ a2,
            float* __restrict__ out)
{
    __shared__ __align__(16) float sT[DCv][520];   // 66.6 KB (pad 8 mod 32 -> 2-way max)
    __shared__ float sMx[DCv], sRZ[DCv];
    __shared__ float sS2[Cv], sT2[Cv];

    const int tid = threadIdx.x;
    const int bf  = blockIdx.x;
    const int b   = bf >> 7;
    const int f   = bf & 127;
    const int t   = tid;
    const int l   = tid & 63, w = tid >> 6;

    // q column (contiguous 128 B/thread) — issue first
    float q[DCv];
    const float* qg = Qws + ((size_t)bf * Tv + t) * DCv;
    #pragma unroll
    for (int j = 0; j < 8; ++j) {
        float4 v = *(const float4*)&qg[j * 4];
        q[4*j] = v.x; q[4*j+1] = v.y; q[4*j+2] = v.z; q[4*j+3] = v.w;
    }

    if (tid < Cv) {
        float s = g2[tid] / sqrtf(v2[tid] + 1e-5f);
        sS2[tid] = s;
        sT2[tid] = (bp[tid] - m2[tid]) * s + be2[tid];
    }
    const float alpha2 = a2[0];

    // O = Mfull * q ; M rows via scalar loads, 4 independent chains per row
    const float* Mg = Mfull + (size_t)bf * 1024;
    float O[DCv];
    #pragma unroll 4
    for (int c = 0; c < DCv; ++c) {
        const float* mr = Mg + c * DCv;
        float a0 = 0.f, a1 = 0.f, a2_ = 0.f, a3 = 0.f;
        #pragma unroll
        for (int k = 0; k < 8; ++k) {
            a0  = fmaf(mr[k],      q[k],      a0);
            a1  = fmaf(mr[k + 8],  q[k + 8],  a1);
            a2_ = fmaf(mr[k + 16], q[k + 16], a2_);
            a3  = fmaf(mr[k + 24], q[k + 24], a3);
        }
        O[c] = (a0 + a1) + (a2_ + a3);
    }

    // causal mask: valid iff t < f + 385 (f+385 <= 512 always)
    const int limit = f + (Tv - Fv + 1);
    if (t >= limit) {
        #pragma unroll
        for (int c = 0; c < DCv; ++c) O[c] = -INFINITY;
    }

    // transpose all 32 rows, then one reduction pass (2 barriers total)
    #pragma unroll
    for (int c = 0; c < DCv; ++c) sT[c][t] = O[c];

    // prefetch residual half 0 under the barrier + reduction
    float rin0[32];
    const float* pin = inp + ((size_t)(b * Cv) * Fv + f) * Tv + t;
    #pragma unroll
    for (int i = 0; i < 32; ++i) rin0[i] = pin[(size_t)i * FT];

    __syncthreads();

    // wave w reduces rows 4w..4w+3 over t (contiguous lane reads, no conflicts)
    #pragma unroll
    for (int r = 0; r < 4; ++r) {
        const int c = w * 4 + r;
        float v[8];
        #pragma unroll
        for (int k = 0; k < 8; ++k) v[k] = sT[c][(k << 6) + l];
        float mx = fmaxf(fmaxf(fmaxf(v[0], v[1]), fmaxf(v[2], v[3])),
                         fmaxf(fmaxf(v[4], v[5]), fmaxf(v[6], v[7])));
        #pragma unroll
        for (int s = 1; s < 64; s <<= 1) mx = fmaxf(mx, __shfl_xor(mx, s));
        float sum = 0.f;
        #pragma unroll
        for (int k = 0; k < 8; ++k) sum += __expf(v[k] - mx);
        #pragma unroll
        for (int s = 1; s < 64; s <<= 1) sum += __shfl_xor(sum, s);
        if (l == 0) { sMx[c] = mx; sRZ[c] = 1.f / sum; }
    }
    __syncthreads();

    // P in registers (masked O=-inf -> 0)
    #pragma unroll
    for (int c = 0; c < DCv; ++c) O[c] = __expf(O[c] - sMx[c]) * sRZ[c];

    // conv2 + BN + PReLU + residual
    float* pot = out + ((size_t)(b * Cv) * Fv + f) * Tv + t;
    #pragma unroll 4
    for (int oo = 0; oo < 32; ++oo) {
        const float* wr = wp + oo * DCv;  // uniform -> scalar loads
        float a0 = 0.f, a1 = 0.f, a2_ = 0.f, a3 = 0.f;
        #pragma unroll
        for (int k = 0; k < 8; ++k) {
            a0  = fmaf(wr[k],      O[k],      a0);
            a1  = fmaf(wr[k + 8],  O[k + 8],  a1);
            a2_ = fmaf(wr[k + 16], O[k + 16], a2_);
            a3  = fmaf(wr[k + 24], O[k + 24], a3);
        }
        float z = fmaf((a0 + a1) + (a2_ + a3), sS2[oo], sT2[oo]);
        z = z >= 0.f ? z : alpha2 * z;
        pot[(size_t)oo * FT] = z + rin0[oo];
    }

    float rin1[32];
    #pragma unroll
    for (int i = 0; i < 32; ++i) rin1[i] = pin[(size_t)(i + 32) * FT];

    #pragma unroll 4
    for (int oo = 0; oo < 32; ++oo) {
        const int o = 32 + oo;
        const float* wr = wp + o * DCv;
        float a0 = 0.f, a1 = 0.f, a2_ = 0.f, a3 = 0.f;
        #pragma unroll
        for (int k = 0; k < 8; ++k) {
            a0  = fmaf(wr[k],      O[k],      a0);
            a1  = fmaf(wr[k + 8],  O[k + 8],  a1);
            a2_ = fmaf(wr[k + 16], O[k + 16], a2_);
            a3  = fmaf(wr[k + 24], O[k + 24], a3);
        }
        float z = fmaf((a0 + a1) + (a2_ + a3), sS2[o], sT2[o]);
        z = z >= 0.f ? z : alpha2 * z;
        pot[(size_t)o * FT] = z + rin1[oo];
    }
}

extern "C" void kernel_launch(void* const* d_in, const int* in_sizes, int n_in,
                              void* d_out, int out_size, void* d_ws, size_t ws_size,
                              hipStream_t stream) {
    const float* inp = (const float*)d_in[0];
    const float* w1  = (const float*)d_in[1];
    const float* b1  = (const float*)d_in[2];
    const float* g1  = (const float*)d_in[3];
    const float* be1 = (const float*)d_in[4];
    const float* m1  = (const float*)d_in[5];
    const float* v1  = (const float*)d_in[6];
    const float* a1  = (const float*)d_in[7];
    const float* wp  = (const float*)d_in[8];
    const float* bp  = (const float*)d_in[9];
    const float* g2  = (const float*)d_in[10];
    const float* be2 = (const float*)d_in[11];
    const float* m2  = (const float*)d_in[12];
    const float* v2  = (const float*)d_in[13];
    const float* a2  = (const float*)d_in[14];

    float* Qws   = (float*)d_ws;                            // 8,388,608 f = 33.6 MB
    float* Mfull = Qws + (size_t)Bv * Fv * Tv * DCv;        //   524,288 f =  2.1 MB

    k1_conv<<<dim3(Bv * Fv * 2), dim3(256), 0, stream>>>(
        inp, w1, b1, g1, be1, m1, v1, a1, Qws);
    km_build<<<dim3(Bv * Fv), dim3(256), 0, stream>>>(Qws, Mfull);
    k2_out<<<dim3(Bv * Fv), dim3(512), 0, stream>>>(
        inp, Qws, Mfull, wp, bp, g2, be2, m2, v2, a2, (float*)d_out);
}

// Round 9
// 121.537 us; speedup vs baseline: 1.4635x; 1.0382x over previous
//
#include <hip/hip_runtime.h>
#include <math.h>

#define Bv  4
#define Cv  64
#define DCv 32
#define Fv  128
#define Tv  512
#define FT  (Fv * 512)

// ---------------------------------------------------------------------------
// K1: PURE conv1 + BN + PReLU -> Q. grid (b,f,half)=1024 x 256, 2-deep
// software pipeline of 8-channel batches. Proven: ~52 VGPR -> 8 blocks/CU.
// ---------------------------------------------------------------------------
#define LOADX(arr, kb) { _Pragma("unroll") \
    for (int i = 0; i < 8; ++i) arr[i] = px[(size_t)((kb) * 8 + i) * FT]; }
#define CONVB(arr, kb) { _Pragma("unroll") \
    for (int c = 0; c < DCv; ++c) { \
        const float* wr = w1 + c * Cv + (kb) * 8; \
        float a = acc[c]; \
        _Pragma("unroll") for (int i = 0; i < 8; ++i) a = fmaf(wr[i], arr[i], a); \
        acc[c] = a; } }

__global__ __launch_bounds__(256, 4)
void k1_conv(const float* __restrict__ inp,
             const float* __restrict__ w1, const float* __restrict__ b1,
             const float* __restrict__ g1, const float* __restrict__ be1,
             const float* __restrict__ m1, const float* __restrict__ v1,
             const float* __restrict__ a1,
             float* __restrict__ Qws)
{
    __shared__ float sS1[DCv], sT1[DCv];

    const int tid  = threadIdx.x;
    const int bid  = blockIdx.x;
    const int half = bid & 1;
    const int bf   = bid >> 1;
    const int b    = bf >> 7;
    const int f    = bf & 127;

    if (tid < DCv) {
        float s = g1[tid] / sqrtf(v1[tid] + 1e-5f);
        sS1[tid] = s;
        sT1[tid] = (b1[tid] - m1[tid]) * s + be1[tid];
    }
    const float alpha1 = a1[0];
    __syncthreads();

    const int t = half * 256 + tid;
    const float* px = inp + ((size_t)(b * Cv) * Fv + f) * Tv + t;

    float acc[DCv];
    #pragma unroll
    for (int c = 0; c < DCv; ++c) acc[c] = 0.f;

    float xa[8], xb[8];
    LOADX(xa, 0);
    LOADX(xb, 1); CONVB(xa, 0);
    LOADX(xa, 2); CONVB(xb, 1);
    LOADX(xb, 3); CONVB(xa, 2);
    LOADX(xa, 4); CONVB(xb, 3);
    LOADX(xb, 5); CONVB(xa, 4);
    LOADX(xa, 6); CONVB(xb, 5);
    LOADX(xb, 7); CONVB(xa, 6);
    CONVB(xb, 7);

    float* qg = Qws + ((size_t)bf * Tv + t) * DCv;
    #pragma unroll
    for (int j = 0; j < 8; ++j) {
        float z0 = fmaf(acc[4*j+0], sS1[4*j+0], sT1[4*j+0]);
        float z1 = fmaf(acc[4*j+1], sS1[4*j+1], sT1[4*j+1]);
        float z2 = fmaf(acc[4*j+2], sS1[4*j+2], sT1[4*j+2]);
        float z3 = fmaf(acc[4*j+3], sS1[4*j+3], sT1[4*j+3]);
        float4 v;
        v.x = z0 >= 0.f ? z0 : alpha1 * z0;
        v.y = z1 >= 0.f ? z1 : alpha1 * z1;
        v.z = z2 >= 0.f ? z2 : alpha1 * z2;
        v.w = z3 >= 0.f ? z3 : alpha1 * z3;
        *(float4*)&qg[j * 4] = v;
    }
}

// ---------------------------------------------------------------------------
// KM: M = Q Q^T / sqrt(32), one block per bf. 256 threads = 4 k-slice groups
// x 64 lanes; lane computes a 4x4 tile over its slice's 128 k's (Q from
// global, L2-hot), partials combined through 16 KB LDS. No atomics, 1 barrier.
// ---------------------------------------------------------------------------
__global__ __launch_bounds__(256)
void km_build(const float* __restrict__ Qws, float* __restrict__ Mfull)
{
    __shared__ __align__(16) float sP[4][1024];  // 16 KB

    const int tid   = threadIdx.x;
    const int bf    = blockIdx.x;
    const int slice = tid >> 6;
    const int l     = tid & 63;
    const int c1b   = l >> 3;
    const int c2b   = l & 7;

    const float* qp = Qws + ((size_t)bf * Tv + slice * 128) * DCv;
    float4 r0 = {0,0,0,0}, r1 = {0,0,0,0}, r2 = {0,0,0,0}, r3 = {0,0,0,0};
    #pragma unroll 4
    for (int i = 0; i < 128; ++i) {
        const float4 qa = *(const float4*)&qp[i * 32 + c1b * 4];
        const float4 qb = *(const float4*)&qp[i * 32 + c2b * 4];
        r0.x = fmaf(qa.x, qb.x, r0.x); r0.y = fmaf(qa.x, qb.y, r0.y);
        r0.z = fmaf(qa.x, qb.z, r0.z); r0.w = fmaf(qa.x, qb.w, r0.w);
        r1.x = fmaf(qa.y, qb.x, r1.x); r1.y = fmaf(qa.y, qb.y, r1.y);
        r1.z = fmaf(qa.y, qb.z, r1.z); r1.w = fmaf(qa.y, qb.w, r1.w);
        r2.x = fmaf(qa.z, qb.x, r2.x); r2.y = fmaf(qa.z, qb.y, r2.y);
        r2.z = fmaf(qa.z, qb.z, r2.z); r2.w = fmaf(qa.z, qb.w, r2.w);
        r3.x = fmaf(qa.w, qb.x, r3.x); r3.y = fmaf(qa.w, qb.y, r3.y);
        r3.z = fmaf(qa.w, qb.z, r3.z); r3.w = fmaf(qa.w, qb.w, r3.w);
    }
    *(float4*)&sP[slice][(c1b * 4 + 0) * DCv + c2b * 4] = r0;
    *(float4*)&sP[slice][(c1b * 4 + 1) * DCv + c2b * 4] = r1;
    *(float4*)&sP[slice][(c1b * 4 + 2) * DCv + c2b * 4] = r2;
    *(float4*)&sP[slice][(c1b * 4 + 3) * DCv + c2b * 4] = r3;
    __syncthreads();

    const float INV = 0.17677669529663687f;  // 1/sqrt(32)
    float4 v0 = *(const float4*)&sP[0][tid * 4];
    float4 v1 = *(const float4*)&sP[1][tid * 4];
    float4 v2 = *(const float4*)&sP[2][tid * 4];
    float4 v3 = *(const float4*)&sP[3][tid * 4];
    float4 o;
    o.x = ((v0.x + v1.x) + (v2.x + v3.x)) * INV;
    o.y = ((v0.y + v1.y) + (v2.y + v3.y)) * INV;
    o.z = ((v0.z + v1.z) + (v2.z + v3.z)) * INV;
    o.w = ((v0.w + v1.w) + (v2.w + v3.w)) * INV;
    *(float4*)&Mfull[(size_t)bf * 1024 + tid * 4] = o;
}

// ---------------------------------------------------------------------------
// K2: fused stats + output, TWO t-columns per thread (tA=tid, tB=tid+256)
// with FUSED inner loops: every M row / W2 row load feeds both columns'
// accumulators -> per-wave load stream halved vs 1-col version. grid 512 x
// 256 threads, 67 KB LDS -> 2 blocks/CU; launch_bounds(256,2) gives the
// allocator a 256-VGPR budget (live set ~140; if it picks 64 it spills ->
// watch WRITE_SIZE).
// ---------------------------------------------------------------------------
__global__ __launch_bounds__(256, 2)
void k2_out(const float* __restrict__ inp,
            const float* __restrict__ Qws, const float* __restrict__ Mfull,
            const float* __restrict__ wp, const float* __restrict__ bp,
            const float* __restrict__ g2, const float* __restrict__ be2,
            const float* __restrict__ m2, const float* __restrict__ v2,
            const float* __restrict__ a2,
            float* __restrict__ out)
{
    __shared__ __align__(16) float sT[DCv][520];   // 66.6 KB
    __shared__ float sMx[DCv], sRZ[DCv];
    __shared__ float sS2[Cv], sT2[Cv];

    const int tid = threadIdx.x;
    const int bf  = blockIdx.x;
    const int b   = bf >> 7;
    const int f   = bf & 127;
    const int tA  = tid;            // 0..255, never masked (limit >= 385)
    const int tB  = tid + 256;      // 256..511
    const int l   = tid & 63, w = tid >> 6;   // 4 waves

    // q columns (contiguous 128 B/thread each) — issue first
    float qA[DCv], qB[DCv];
    const float* qgA = Qws + ((size_t)bf * Tv + tA) * DCv;
    const float* qgB = qgA + 256 * DCv;
    #pragma unroll
    for (int j = 0; j < 8; ++j) {
        float4 vA = *(const float4*)&qgA[j * 4];
        float4 vB = *(const float4*)&qgB[j * 4];
        qA[4*j] = vA.x; qA[4*j+1] = vA.y; qA[4*j+2] = vA.z; qA[4*j+3] = vA.w;
        qB[4*j] = vB.x; qB[4*j+1] = vB.y; qB[4*j+2] = vB.z; qB[4*j+3] = vB.w;
    }

    if (tid < Cv) {
        float s = g2[tid] / sqrtf(v2[tid] + 1e-5f);
        sS2[tid] = s;
        sT2[tid] = (bp[tid] - m2[tid]) * s + be2[tid];
    }
    const float alpha2 = a2[0];

    // O = Mfull * q for BOTH columns; each mr[k] load feeds 2 FMAs
    const float* Mg = Mfull + (size_t)bf * 1024;
    float OA[DCv], OB[DCv];
    #pragma unroll 4
    for (int c = 0; c < DCv; ++c) {
        const float* mr = Mg + c * DCv;
        float aA0 = 0.f, aA1 = 0.f, aB0 = 0.f, aB1 = 0.f;
        #pragma unroll
        for (int k = 0; k < 16; ++k) {
            const float m0 = mr[k], m1 = mr[k + 16];
            aA0 = fmaf(m0, qA[k],      aA0);
            aA1 = fmaf(m1, qA[k + 16], aA1);
            aB0 = fmaf(m0, qB[k],      aB0);
            aB1 = fmaf(m1, qB[k + 16], aB1);
        }
        OA[c] = aA0 + aA1;
        OB[c] = aB0 + aB1;
    }

    // causal mask: valid iff t < f + 385; only column B can be masked
    const int limit = f + (Tv - Fv + 1);
    if (tB >= limit) {
        #pragma unroll
        for (int c = 0; c < DCv; ++c) OB[c] = -INFINITY;
    }

    // transpose both columns into the tile
    #pragma unroll
    for (int c = 0; c < DCv; ++c) sT[c][tA] = OA[c];
    #pragma unroll
    for (int c = 0; c < DCv; ++c) sT[c][tB] = OB[c];

    // prefetch residual half 0 for both columns (lands under the reduction)
    float rinA0[32], rinB0[32];
    const float* pin = inp + ((size_t)(b * Cv) * Fv + f) * Tv + tA;
    #pragma unroll
    for (int i = 0; i < 32; ++i) {
        rinA0[i] = pin[(size_t)i * FT];
        rinB0[i] = pin[(size_t)i * FT + 256];
    }

    __syncthreads();

    // reduction: 4 waves x 8 rows each (contiguous lane reads, conflict-free)
    #pragma unroll
    for (int r = 0; r < 8; ++r) {
        const int c = w * 8 + r;
        float v[8];
        #pragma unroll
        for (int k = 0; k < 8; ++k) v[k] = sT[c][(k << 6) + l];
        float mx = fmaxf(fmaxf(fmaxf(v[0], v[1]), fmaxf(v[2], v[3])),
                         fmaxf(fmaxf(v[4], v[5]), fmaxf(v[6], v[7])));
        #pragma unroll
        for (int s = 1; s < 64; s <<= 1) mx = fmaxf(mx, __shfl_xor(mx, s));
        float sum = 0.f;
        #pragma unroll
        for (int k = 0; k < 8; ++k) sum += __expf(v[k] - mx);
        #pragma unroll
        for (int s = 1; s < 64; s <<= 1) sum += __shfl_xor(sum, s);
        if (l == 0) { sMx[c] = mx; sRZ[c] = 1.f / sum; }
    }
    __syncthreads();

    // normalize in registers (masked OB=-inf -> 0)
    #pragma unroll
    for (int c = 0; c < DCv; ++c) {
        const float mx = sMx[c], rz = sRZ[c];
        OA[c] = __expf(OA[c] - mx) * rz;
        OB[c] = __expf(OB[c] - mx) * rz;
    }

    // conv2 + BN + PReLU + residual; each wr[k] load feeds both columns
    float* pot = out + ((size_t)(b * Cv) * Fv + f) * Tv + tA;
    #pragma unroll 4
    for (int oo = 0; oo < 32; ++oo) {
        const float* wr = wp + oo * DCv;
        float aA0 = 0.f, aA1 = 0.f, aB0 = 0.f, aB1 = 0.f;
        #pragma unroll
        for (int k = 0; k < 16; ++k) {
            const float w0 = wr[k], w1_ = wr[k + 16];
            aA0 = fmaf(w0,  OA[k],      aA0);
            aA1 = fmaf(w1_, OA[k + 16], aA1);
            aB0 = fmaf(w0,  OB[k],      aB0);
            aB1 = fmaf(w1_, OB[k + 16], aB1);
        }
        float zA = fmaf(aA0 + aA1, sS2[oo], sT2[oo]);
        float zB = fmaf(aB0 + aB1, sS2[oo], sT2[oo]);
        zA = zA >= 0.f ? zA : alpha2 * zA;
        zB = zB >= 0.f ? zB : alpha2 * zB;
        pot[(size_t)oo * FT]       = zA + rinA0[oo];
        pot[(size_t)oo * FT + 256] = zB + rinB0[oo];
    }

    // prefetch residual half 1
    float rinA1[32], rinB1[32];
    #pragma unroll
    for (int i = 0; i < 32; ++i) {
        rinA1[i] = pin[(size_t)(i + 32) * FT];
        rinB1[i] = pin[(size_t)(i + 32) * FT + 256];
    }

    #pragma unroll 4
    for (int oo = 0; oo < 32; ++oo) {
        const int o = 32 + oo;
        const float* wr = wp + o * DCv;
        float aA0 = 0.f, aA1 = 0.f, aB0 = 0.f, aB1 = 0.f;
        #pragma unroll
        for (int k = 0; k < 16; ++k) {
            const float w0 = wr[k], w1_ = wr[k + 16];
            aA0 = fmaf(w0,  OA[k],      aA0);
            aA1 = fmaf(w1_, OA[k + 16], aA1);
            aB0 = fmaf(w0,  OB[k],      aB0);
            aB1 = fmaf(w1_, OB[k + 16], aB1);
        }
        float zA = fmaf(aA0 + aA1, sS2[o], sT2[o]);
        float zB = fmaf(aB0 + aB1, sS2[o], sT2[o]);
        zA = zA >= 0.f ? zA : alpha2 * zA;
        zB = zB >= 0.f ? zB : alpha2 * zB;
        pot[(size_t)o * FT]       = zA + rinA1[oo];
        pot[(size_t)o * FT + 256] = zB + rinB1[oo];
    }
}

extern "C" void kernel_launch(void* const* d_in, const int* in_sizes, int n_in,
                              void* d_out, int out_size, void* d_ws, size_t ws_size,
                              hipStream_t stream) {
    const float* inp = (const float*)d_in[0];
    const float* w1  = (const float*)d_in[1];
    const float* b1  = (const float*)d_in[2];
    const float* g1  = (const float*)d_in[3];
    const float* be1 = (const float*)d_in[4];
    const float* m1  = (const float*)d_in[5];
    const float* v1  = (const float*)d_in[6];
    const float* a1  = (const float*)d_in[7];
    const float* wp  = (const float*)d_in[8];
    const float* bp  = (const float*)d_in[9];
    const float* g2  = (const float*)d_in[10];
    const float* be2 = (const float*)d_in[11];
    const float* m2  = (const float*)d_in[12];
    const float* v2  = (const float*)d_in[13];
    const float* a2  = (const float*)d_in[14];

    float* Qws   = (float*)d_ws;                            // 8,388,608 f = 33.6 MB
    float* Mfull = Qws + (size_t)Bv * Fv * Tv * DCv;        //   524,288 f =  2.1 MB

    k1_conv<<<dim3(Bv * Fv * 2), dim3(256), 0, stream>>>(
        inp, w1, b1, g1, be1, m1, v1, a1, Qws);
    km_build<<<dim3(Bv * Fv), dim3(256), 0, stream>>>(Qws, Mfull);
    k2_out<<<dim3(Bv * Fv), dim3(256), 0, stream>>>(
        inp, Qws, Mfull, wp, bp, g2, be2, m2, v2, a2, (float*)d_out);
}